// Round 6
// baseline (15179.836 us; speedup 1.0000x reference)
//
#include <hip/hip_runtime.h>
#include <hip/hip_bf16.h>
#include <stdint.h>

// RVAE forward: 3 sequential GRU scans (L=512, B=256, H=256) on 256 WGs x 512 thr.
// Group g (wgid&31) owns batch rows [8g,8g+8); slice s (wgid>>5) owns units [32s,32s+32).
// R6: thread-per-(row,unit,khalf) GEMV with Whh/Wih in LDS; single quad_perm xor-1
// reduce; flag-based data-ready exchange (no atomic counter); posterior computed from
// staged full-h (zpart exchange eliminated); xh packed bf16x2.

#define EXTF 11840
#define POOLF (24576 + EXTF)

struct RvaeParams {
  const float *x, *eps;
  const float *fx_W, *fx_b;
  const float *fz_W1, *fz_b1, *fz_W2, *fz_b2;
  const float *p1_Wih, *p1_Whh, *p1_bih, *p1_bhh;
  const float *p2_Wih, *p2_Whh, *p2_bih, *p2_bhh;
  const float *pn_locW, *pn_locb, *pn_scaleW, *pn_scaleb;
  const float *th_Wih, *th_Whh, *th_bih, *th_bhh;
  const float *tn_locW, *tn_locb;
  float* out;
  unsigned* flags;   // [32 groups][8 slices] monotone step tags
  float* hbuf;       // [2][256][256] parity-double-buffered hidden state (sc1/LLC)
  float* zf_seq;     // [512][256][32]
  unsigned* xh;      // [512 t][256 row][128] packed 2x bf16 units
};

__device__ __forceinline__ float agent_load_f32(const float* p) {
  return __hip_atomic_load(p, __ATOMIC_RELAXED, __HIP_MEMORY_SCOPE_AGENT);
}
__device__ __forceinline__ unsigned agent_load_u32(const unsigned* p) {
  return __hip_atomic_load(p, __ATOMIC_RELAXED, __HIP_MEMORY_SCOPE_AGENT);
}
__device__ __forceinline__ unsigned long long agent_load_u64(const unsigned long long* p) {
  return __hip_atomic_load(p, __ATOMIC_RELAXED, __HIP_MEMORY_SCOPE_AGENT);
}
__device__ __forceinline__ void agent_store_f32(float* p, float v) {
  __hip_atomic_store(p, v, __ATOMIC_RELAXED, __HIP_MEMORY_SCOPE_AGENT);
}
__device__ __forceinline__ void agent_store_u32(unsigned* p, unsigned v) {
  __hip_atomic_store(p, v, __ATOMIC_RELAXED, __HIP_MEMORY_SCOPE_AGENT);
}
__device__ __forceinline__ float sigm(float v) { return 1.0f / (1.0f + __expf(-v)); }
__device__ __forceinline__ float ftanh(float v) { return 1.0f - 2.0f / (__expf(2.0f * v) + 1.0f); }
__device__ __forceinline__ float softplusf(float v) { return (v > 15.0f) ? v : log1pf(__expf(v)); }
__device__ __forceinline__ unsigned f2bf(float x) {  // round-to-nearest-even bf16
  unsigned uu = __float_as_uint(x);
  return (uu + 0x7fffu + ((uu >> 16) & 1u)) >> 16;
}
template<int CTRL>
__device__ __forceinline__ float dpp_add(float v) {  // v += dpp(v)
  int xi = __builtin_amdgcn_update_dpp(0, __float_as_int(v), CTRL, 0xF, 0xF, true);
  return v + __int_as_float(xi);
}
__device__ __forceinline__ float dpp_xor1_add(float v) {  // quad_perm [1,0,3,2]
  int xi = __builtin_amdgcn_update_dpp(0, __float_as_int(v), 0xB1, 0xF, 0xF, true);
  return v + __int_as_float(xi);
}

extern "C" __global__ void __launch_bounds__(512, 2) rvae_main(RvaeParams P) {
  __shared__ __align__(16) float POOL[POOLF];  // Wh[24576] + phase-repartitioned EXT
  __shared__ float bihL[96], bhhL[96];
  __shared__ float fxwL[64], fxbL[64];
  __shared__ float fzW1L[8], fzb1L[2], fzW2L[64], fzb2L[32];
  __shared__ float pnlb[4], pnsb[4], tnwL[32];
  __shared__ float pvL[8 * 36];

  const int tid = threadIdx.x;
  const int wgid = blockIdx.x;
  const int s = wgid >> 5, g = wgid & 31;
  const int u = tid >> 4, bq = (tid >> 1) & 7, kh = tid & 1;
  const int lane = tid & 63;
  float* Wh = POOL;            // [3][32][256]
  float* EXT = POOL + 24576;
  unsigned* gflags = P.flags + g * 8;

  if (tid < 64) { fxwL[tid] = P.fx_W[tid]; fxbL[tid] = P.fx_b[tid]; fzW2L[tid] = P.fz_W2[tid]; }
  if (tid < 8)  fzW1L[tid] = P.fz_W1[tid];
  if (tid < 2)  fzb1L[tid] = P.fz_b1[tid];
  if (tid < 32) { fzb2L[tid] = P.fz_b2[tid]; tnwL[tid] = P.tn_locW[s * 32 + tid]; }
  if (tid < 4)  { pnlb[tid] = P.pn_locb[tid]; pnsb[tid] = P.pn_scaleb[tid]; }

  auto poll = [&](unsigned tag) {
    int guard = 0;
    for (;;) {
      unsigned f = agent_load_u32(gflags + (lane & 7));
      if (__all((int)(f >= tag))) break;
      __builtin_amdgcn_s_sleep(1);
      if (++guard > (1 << 20)) break;  // fail loud, never hang
    }
  };
  auto publish = [&](unsigned tag) {
    asm volatile("s_waitcnt vmcnt(0)" ::: "memory");  // h/xh/zf stores reached LLC
    __syncthreads();                                  // all waves drained
    if (tid == 0) agent_store_u32(gflags + s, tag);
  };
  auto load_Wh = [&](const float* Whh) {
    for (int i = tid; i < 6144; i += 512) {
      int r = i >> 6, c4 = (i & 63) << 2, gate = r >> 5, uu = r & 31;
      *(float4*)(Wh + r * 256 + c4) =
          *(const float4*)(Whh + (size_t)(gate * 256 + s * 32 + uu) * 256 + c4);
    }
  };
  auto load_Wi64 = [&](const float* Wih) {
    for (int i = tid; i < 1536; i += 512) {
      int r = i >> 4, c4 = (i & 15) << 2, gate = r >> 5, uu = r & 31;
      *(float4*)(EXT + r * 64 + c4) =
          *(const float4*)(Wih + (size_t)(gate * 256 + s * 32 + uu) * 64 + c4);
    }
  };
  auto load_Wi32 = [&](const float* Wih) {
    for (int i = tid; i < 768; i += 512) {
      int r = i >> 3, c4 = (i & 7) << 2, gate = r >> 5, uu = r & 31;
      *(float4*)(EXT + r * 32 + c4) =
          *(const float4*)(Wih + (size_t)(gate * 256 + s * 32 + uu) * 32 + c4);
    }
  };
  auto load_bias = [&](const float* bih, const float* bhh) {
    if (tid < 96) {
      int gate = tid >> 5, uu = tid & 31;
      bihL[tid] = bih[gate * 256 + s * 32 + uu];
      bhhL[tid] = bhh[gate * 256 + s * 32 + uu];
    }
  };
  auto h_issue = [&](int par, unsigned long long& qa, unsigned long long& qb) {
    const unsigned long long* hb =
        (const unsigned long long*)(P.hbuf + par * 65536 + g * 2048) + tid * 2;
    qa = agent_load_u64(hb); qb = agent_load_u64(hb + 1);
  };
  auto h_write = [&](float* hLp, unsigned long long qa, unsigned long long qb, bool zero) {
    int row = tid >> 6, k0 = (tid & 63) << 2;
    float4 v;
    if (zero) { v = make_float4(0.f, 0.f, 0.f, 0.f); }
    else {
      union { unsigned long long q[2]; float f[4]; } cv; cv.q[0] = qa; cv.q[1] = qb;
      v = *(float4*)cv.f;
    }
    *(float4*)(hLp + row * 260 + k0) = v;   // stride 260: conflict-free kh/bq reads
  };
  auto gi = [&](const float* inLp, int K, int stride, float& gr, float& gz, float& gn) {
    int k0 = kh * (K >> 1);
    const float4* iv = (const float4*)(inLp + bq * stride + k0);
    const float4* wr = (const float4*)(EXT + u * K + k0);
    const float4* wz = (const float4*)(EXT + 32 * K + u * K + k0);
    const float4* wn = (const float4*)(EXT + 64 * K + u * K + k0);
    float r = 0.f, z = 0.f, n = 0.f;
    int nc = K >> 3;
#pragma unroll 4
    for (int c = 0; c < nc; ++c) {
      float4 hv = iv[c], a = wr[c], b2 = wz[c], d = wn[c];
      r = fmaf(a.x, hv.x, r); r = fmaf(a.y, hv.y, r); r = fmaf(a.z, hv.z, r); r = fmaf(a.w, hv.w, r);
      z = fmaf(b2.x, hv.x, z); z = fmaf(b2.y, hv.y, z); z = fmaf(b2.z, hv.z, z); z = fmaf(b2.w, hv.w, z);
      n = fmaf(d.x, hv.x, n); n = fmaf(d.y, hv.y, n); n = fmaf(d.z, hv.z, n); n = fmaf(d.w, hv.w, n);
    }
    gr = r; gz = z; gn = n;
  };
  // Full GRU gate update: thread (bq,u,kh) owns output unit (s*32+u) of row bq.
  auto gru_core = [&](float* hLp, float gir, float giz, float gin, int outPar) -> float {
    const float4* hp = (const float4*)(hLp + bq * 260 + kh * 128);
    const float4* wr = (const float4*)(Wh + u * 256 + kh * 128);
    const float4* wz = (const float4*)(Wh + 8192 + u * 256 + kh * 128);
    const float4* wn = (const float4*)(Wh + 16384 + u * 256 + kh * 128);
    float ar = gir, az = giz, an = 0.f;
#pragma unroll 8
    for (int c = 0; c < 32; ++c) {
      float4 hv = hp[c];
      float4 a = wr[c], b2 = wz[c], d = wn[c];
      ar = fmaf(a.x, hv.x, ar); ar = fmaf(a.y, hv.y, ar);
      ar = fmaf(a.z, hv.z, ar); ar = fmaf(a.w, hv.w, ar);
      az = fmaf(b2.x, hv.x, az); az = fmaf(b2.y, hv.y, az);
      az = fmaf(b2.z, hv.z, az); az = fmaf(b2.w, hv.w, az);
      an = fmaf(d.x, hv.x, an); an = fmaf(d.y, hv.y, an);
      an = fmaf(d.z, hv.z, an); an = fmaf(d.w, hv.w, an);
    }
    ar = dpp_xor1_add(ar); az = dpp_xor1_add(az);      // cross-khalf sum (lane^1)
    float ani = dpp_xor1_add(gin); an = dpp_xor1_add(an);
    float rr = sigm(ar + bihL[u] + bhhL[u]);
    float zz = sigm(az + bihL[32 + u] + bhhL[32 + u]);
    float nn = ftanh(fmaf(rr, an + bhhL[64 + u], ani + bihL[64 + u]));
    float hold = hLp[bq * 260 + s * 32 + u];
    float hnew = fmaf(zz, hold - nn, nn);
    if (kh == 0)
      agent_store_f32(P.hbuf + outPar * 65536 + (g * 8 + bq) * 256 + s * 32 + u, hnew);
    return hnew;
  };

  //================= Phase 1: backward GRU (phi1), xh packed bf16 =================
  load_Wh(P.p1_Whh); load_Wi64(P.p1_Wih); load_bias(P.p1_bih, P.p1_bhh);
  {
    float* inL1 = EXT + 6144;  // [8][68]
    float* hL1  = EXT + 6688;  // [8][260]
    __syncthreads();
    { int bb = tid >> 6, k = tid & 63;
      float xv = P.x[(size_t)(g * 8 + bb) * 512 + 511];
      inL1[bb * 68 + k] = ftanh(fmaf(xv, fxwL[k], fxbL[k])); }
    __syncthreads();
#pragma unroll 1
    for (int t = 0; t < 512; ++t) {
      unsigned long long qa = 0, qb = 0;
      if (t) { poll(t); h_issue(t & 1, qa, qb); }
      float gr, gz, gn;
      gi(inL1, 64, 68, gr, gz, gn);          // overlaps LLC h latency
      h_write(hL1, qa, qb, t == 0);
      __syncthreads();
      float hnew = gru_core(hL1, gr, gz, gn, (t + 1) & 1);
      int t_in = 511 - t;
      {
        float hp2 = __shfl_xor(hnew, 16);    // partner unit u^1
        if (kh == 0 && (u & 1) == 0) {
          unsigned pk = f2bf(hnew) | (f2bf(hp2) << 16);
          agent_store_u32(P.xh + (size_t)t_in * 32768 + (g * 8 + bq) * 128 + s * 16 + (u >> 1), pk);
        }
      }
      if (t < 511) {  // featurize next input col; publish's sync orders vs next gi
        int bb = tid >> 6, k = tid & 63;
        float xv = P.x[(size_t)(g * 8 + bb) * 512 + (t_in - 1)];
        inL1[bb * 68 + k] = ftanh(fmaf(xv, fxwL[k], fxbL[k]));
      }
      publish(t + 1);
    }
  }

  //================= Phase 2: encoder GRU + posterior + feat_z =================
  load_Wh(P.p2_Whh); load_Wi32(P.p2_Wih); load_bias(P.p2_bih, P.p2_bhh);
  {
    float* SBp  = EXT + 3072;   // [8][520] posterior loc(0..3)/scale(4..7) weights
    float* xhL  = EXT + 7232;   // [8][264]
    float* inL2 = EXT + 9344;   // [8][36] zf features
    float* hL2  = EXT + 9632;   // [8][260]
    float* pL   = EXT + 11712;  // [8][9]
    float* hmL2 = EXT + 11784;  // [8][2]
    for (int i = tid; i < 2048; i += 512) {
      int o = i >> 9, c = i & 511;
      SBp[o * 520 + c] = P.pn_locW[i];
      SBp[(4 + o) * 520 + c] = P.pn_scaleW[i];
    }
    for (int i = tid; i < 288; i += 512) inL2[i] = 0.f;  // zf0 = 0
    poll(512);                  // phase entry: everyone finished phase 1
    __syncthreads();
    auto stage_xh_w = [&](unsigned xa, unsigned xb) {
      int w0 = tid, w1 = tid + 512;
      xhL[(w0 >> 7) * 264 + ((w0 & 127) << 1)]     = __uint_as_float((xa & 0xffffu) << 16);
      xhL[(w0 >> 7) * 264 + ((w0 & 127) << 1) + 1] = __uint_as_float(xa & 0xffff0000u);
      xhL[(w1 >> 7) * 264 + ((w1 & 127) << 1)]     = __uint_as_float((xb & 0xffffu) << 16);
      xhL[(w1 >> 7) * 264 + ((w1 & 127) << 1) + 1] = __uint_as_float(xb & 0xffff0000u);
    };
    auto pblock = [&](int tp, bool toIn) {  // z_tp = posterior(staged zh, xh_tp)
      {
        int b = tid >> 6, o = (tid >> 3) & 7, c = tid & 7;
        const float* base = (c < 4) ? (hL2 + b * 260 + c * 64) : (xhL + b * 264 + (c - 4) * 64);
        const float* wrow = SBp + o * 520 + c * 64;
        float acc = 0.f;
#pragma unroll
        for (int m = 0; m < 16; ++m) {
          int mi = ((m + 2 * c) & 15) << 2;  // rotation: de-conflicts banks
          float4 v = *(const float4*)(base + mi);
          float4 w = *(const float4*)(wrow + mi);
          acc = fmaf(v.x, w.x, fmaf(v.y, w.y, fmaf(v.z, w.z, fmaf(v.w, w.w, acc))));
        }
        acc = dpp_add<0x111>(acc); acc = dpp_add<0x112>(acc); acc = dpp_add<0x114>(acc);
        if (c == 7) pL[b * 9 + o] = acc;
      }
      __syncthreads();
      if (tid < 16) {
        int bb = tid >> 1, m = tid & 1;
        float a = fzb1L[m];
#pragma unroll
        for (int zi = 0; zi < 4; ++zi) {
          float loc = pL[bb * 9 + zi] + pnlb[zi];
          float sc = softplusf(pL[bb * 9 + 4 + zi] + pnsb[zi]);
          float e = P.eps[((size_t)tp * 256 + g * 8 + bb) * 4 + zi];
          a = fmaf(fmaf(sc, e, loc), fzW1L[m * 4 + zi], a);
        }
        hmL2[bb * 2 + m] = ftanh(a);
      }
      __syncthreads();
      if (tid < 256) {
        int bb = tid >> 5, o = tid & 31;
        float zf = ftanh(fmaf(hmL2[bb * 2], fzW2L[o * 2],
                         fmaf(hmL2[bb * 2 + 1], fzW2L[o * 2 + 1], fzb2L[o])));
        if (toIn) inL2[bb * 36 + o] = zf;
        if (s == 0) agent_store_f32(P.zf_seq + ((size_t)tp * 256 + g * 8 + bb) * 32 + o, zf);
      }
      __syncthreads();
    };
#pragma unroll 1
    for (int t = 0; t < 512; ++t) {
      unsigned long long qa = 0, qb = 0; unsigned xa = 0, xb = 0;
      if (t) {
        poll(1024 + t);
        h_issue(t & 1, qa, qb);
        const unsigned* xp = P.xh + (size_t)(t - 1) * 32768 + g * 1024;
        xa = agent_load_u32(xp + tid); xb = agent_load_u32(xp + tid + 512);
      }
      h_write(hL2, qa, qb, t == 0);
      if (t) stage_xh_w(xa, xb);
      __syncthreads();
      if (t) pblock(t - 1, true);         // z_{t-1} -> zf_t into inL2
      float gr, gz, gn;
      gi(inL2, 32, 36, gr, gz, gn);
      gru_core(hL2, gr, gz, gn, (t + 1) & 1);
      publish(1024 + t + 1);
    }
    { // epilogue: z_511 from zh_512 (parity 0)
      poll(1536);
      unsigned long long qa, qb; h_issue(0, qa, qb);
      const unsigned* xp = P.xh + (size_t)511 * 32768 + g * 1024;
      unsigned xa = agent_load_u32(xp + tid), xb = agent_load_u32(xp + tid + 512);
      h_write(hL2, qa, qb, false);
      stage_xh_w(xa, xb);
      __syncthreads();
      pblock(511, false);
      __syncthreads();
    }
  }

  //================= Phase 3: decoder GRU + output projection =================
  load_Wh(P.th_Whh); load_Wi32(P.th_Wih); load_bias(P.th_bih, P.th_bhh);
  {
    float* inL3 = EXT + 3072;  // [8][36]
    float* hL3  = EXT + 3360;  // [8][260]
    const float tnb = P.tn_locb[0];
    __syncthreads();
#pragma unroll 1
    for (int t = 0; t < 512; ++t) {
      float zfv = 0.f;
      if (tid < 256)
        zfv = agent_load_f32(P.zf_seq + ((size_t)t * 256 + g * 8 + (tid >> 5)) * 32 + (tid & 31));
      unsigned long long qa = 0, qb = 0;
      if (t) { poll(2048 + t); h_issue(t & 1, qa, qb); }
      if (tid < 256) inL3[(tid >> 5) * 36 + (tid & 31)] = zfv;
      h_write(hL3, qa, qb, t == 0);
      __syncthreads();
      float gr, gz, gn;
      gi(inL3, 32, 36, gr, gz, gn);
      float hnew = gru_core(hL3, gr, gz, gn, (t + 1) & 1);
      if (kh == 0) pvL[bq * 36 + u] = hnew * tnwL[u];
      publish(2048 + t + 1);
      if (tid < 8) {   // per-slice partial of the output dot; 8 slices atomicAdd
        float acc = (s == 0) ? tnb : 0.f;
#pragma unroll 8
        for (int i = 0; i < 32; ++i) acc += pvL[tid * 36 + i];
        atomicAdd(P.out + (size_t)(g * 8 + tid) * 512 + t, acc);
      }
    }
  }
}

extern "C" void kernel_launch(void* const* d_in, const int* in_sizes, int n_in,
                              void* d_out, int out_size, void* d_ws, size_t ws_size,
                              hipStream_t stream) {
  (void)in_sizes; (void)n_in; (void)ws_size;
  RvaeParams P;
  P.x        = (const float*)d_in[0];
  P.eps      = (const float*)d_in[1];
  P.fx_W     = (const float*)d_in[2];  P.fx_b     = (const float*)d_in[3];
  P.fz_W1    = (const float*)d_in[4];  P.fz_b1    = (const float*)d_in[5];
  P.fz_W2    = (const float*)d_in[6];  P.fz_b2    = (const float*)d_in[7];
  P.p1_Wih   = (const float*)d_in[8];  P.p1_Whh   = (const float*)d_in[9];
  P.p1_bih   = (const float*)d_in[10]; P.p1_bhh   = (const float*)d_in[11];
  P.p2_Wih   = (const float*)d_in[12]; P.p2_Whh   = (const float*)d_in[13];
  P.p2_bih   = (const float*)d_in[14]; P.p2_bhh   = (const float*)d_in[15];
  P.pn_locW  = (const float*)d_in[16]; P.pn_locb  = (const float*)d_in[17];
  P.pn_scaleW= (const float*)d_in[18]; P.pn_scaleb= (const float*)d_in[19];
  P.th_Wih   = (const float*)d_in[20]; P.th_Whh   = (const float*)d_in[21];
  P.th_bih   = (const float*)d_in[22]; P.th_bhh   = (const float*)d_in[23];
  P.tn_locW  = (const float*)d_in[24]; P.tn_locb  = (const float*)d_in[25];
  P.out = (float*)d_out;
  char* ws = (char*)d_ws;
  P.flags  = (unsigned*)ws;                                 // 1 KB used (zeroed)
  P.hbuf   = (float*)(ws + 4096);                           // 524288 B
  P.zf_seq = (float*)(ws + 4096 + 524288);                  // 16777216 B
  P.xh     = (unsigned*)(ws + 4096 + 524288 + 16777216);    // 67108864 B

  hipMemsetAsync(d_out, 0, (size_t)out_size * sizeof(float), stream);
  hipMemsetAsync(d_ws, 0, 4096, stream);
  void* args[] = { (void*)&P };
  hipError_t err = hipLaunchCooperativeKernel((void*)rvae_main, dim3(256), dim3(512), args, 0, stream);
  if (err != hipSuccess) {
    hipLaunchKernelGGL(rvae_main, dim3(256), dim3(512), 0, stream, P);
  }
}